// Round 8
// baseline (296.075 us; speedup 1.0000x reference)
//
#include <hip/hip_runtime.h>
#include <hip/hip_bf16.h>
#include <math.h>

// Problem constants
#define B_ 64
#define L_ 256
#define H_ 1024
#define P_ 64
#define A_ 512
#define T_ 8
#define KDIM 1152  // H + 2P

typedef __attribute__((ext_vector_type(8))) __bf16 bf16x8;
typedef __attribute__((ext_vector_type(4))) float f32x4;

__device__ __forceinline__ float bf2f(ushort u) {
  union { unsigned int i; float f; } v; v.i = ((unsigned int)u) << 16; return v.f;
}
__device__ __forceinline__ ushort f2bf_rne(float f) {
  union { float f; unsigned int i; } v; v.f = f;
  unsigned int r = v.i + 0x7FFFu + ((v.i >> 16) & 1u);  // RNE
  return (ushort)(r >> 16);
}
__device__ __forceinline__ unsigned int pack2_rne(float a, float b) {
  return (unsigned int)f2bf_rne(a) | ((unsigned int)f2bf_rne(b) << 16);
}

// scalar load: element i of a buffer that is bf16 if BF16 else fp32
template <bool BF16>
__device__ __forceinline__ float ld1(const void* p, size_t i) {
  if (BF16) return bf2f(((const ushort*)p)[i]);
  return ((const float*)p)[i];
}
// 4-wide load, i must be a multiple of 4
template <bool BF16>
__device__ __forceinline__ float4 ld4(const void* p, size_t i) {
  if (BF16) {
    ushort4 u = *(const ushort4*)((const ushort*)p + i);
    return (float4){bf2f(u.x), bf2f(u.y), bf2f(u.z), bf2f(u.w)};
  }
  return *(const float4*)((const float*)p + i);
}

// ---------------------------------------------------------------------------
// Kernel 0: dtype detector. word_hiddens ~ N(0,1). Genuine bf16 ushorts have
// exponent byte in [110,135] ~99% of the time; fp32 data read as ushorts has
// uniform exponent bytes in the low halves (~54% pass overall).
// ---------------------------------------------------------------------------
__global__ __launch_bounds__(256) void detect_dtype(const ushort* __restrict__ wh,
                                                    int* __restrict__ flag) {
  __shared__ int cnt;
  if (threadIdx.x == 0) cnt = 0;
  __syncthreads();
  int c = 0;
  for (int i = threadIdx.x; i < 8192; i += 256) {
    int e = (wh[i] >> 7) & 0xFF;
    if (e >= 110 && e <= 135) c++;
  }
  atomicAdd(&cnt, c);
  __syncthreads();
  if (threadIdx.x == 0) flag[0] = (cnt > 6553) ? 1 : 0;  // >80% plausible -> bf16
}

// ---------------------------------------------------------------------------
// Kernel 1: W_pos [1152][512] -> WT [512][1152] bf16 (B^T layout for MFMA)
// grid 576 = 16 (a-tiles) x 36 (f-tiles), block 256 (32x8)
// ---------------------------------------------------------------------------
template <bool BF16>
__global__ __launch_bounds__(256) void transpose_wpos(const void* __restrict__ W,
                                                      ushort* __restrict__ WT,
                                                      const int* __restrict__ flag) {
  if ((*flag != 0) != BF16) return;
  __shared__ ushort tile[32][33];
  const int bx = blockIdx.x & 15;   // a tile
  const int by = blockIdx.x >> 4;   // f tile
  const int tx = threadIdx.x & 31;
  const int ty = threadIdx.x >> 5;  // 0..7
#pragma unroll
  for (int i = 0; i < 4; ++i) {
    size_t idx = (size_t)(by * 32 + ty + i * 8) * A_ + bx * 32 + tx;
    ushort u;
    if (BF16) u = ((const ushort*)W)[idx];
    else u = f2bf_rne(((const float*)W)[idx]);
    tile[ty + i * 8][tx] = u;
  }
  __syncthreads();
#pragma unroll
  for (int i = 0; i < 4; ++i) {
    WT[(size_t)(bx * 32 + ty + i * 8) * KDIM + by * 32 + tx] = tile[tx][ty + i * 8];
  }
}

// ---------------------------------------------------------------------------
// Kernel E1: entity features EF[64][4096] fp32 = [e1_h | e1_type | e2_h | e2_type]
// grid 64 (one block per batch), block 256
// ---------------------------------------------------------------------------
template <bool BF16>
__global__ __launch_bounds__(256) void entity_features_k(
    const void* __restrict__ wh, const int* __restrict__ e1e,
    const int* __restrict__ e2e, const void* __restrict__ temb,
    float* __restrict__ EF, const int* __restrict__ flag) {
  if ((*flag != 0) != BF16) return;
  const int b = blockIdx.x;
  const int tid = threadIdx.x;
  __shared__ float eh1[1024];
  __shared__ float eh2[1024];
  __shared__ float part[256][16];
  __shared__ float scores[16];
  __shared__ float alpha[16];

  const size_t o1 = ((size_t)b * L_ + e1e[b]) * H_;
  const size_t o2 = ((size_t)b * L_ + e2e[b]) * H_;
  for (int h = tid; h < 1024; h += 256) {
    eh1[h] = ld1<BF16>(wh, o1 + h);
    eh2[h] = ld1<BF16>(wh, o2 + h);
  }
  __syncthreads();

  float p[16];
#pragma unroll
  for (int t = 0; t < 16; ++t) p[t] = 0.f;
  for (int h = tid; h < 1024; h += 256) {
    float a1 = eh1[h], a2 = eh2[h];
#pragma unroll
    for (int t = 0; t < 8; ++t) {
      float c = ld1<BF16>(temb, t * 1024 + h);
      p[t] += a1 * c;
      p[8 + t] += a2 * c;
    }
  }
#pragma unroll
  for (int t = 0; t < 16; ++t) part[tid][t] = p[t];
  __syncthreads();
  if (tid < 16) {
    float s = 0.f;
    for (int i = 0; i < 256; ++i) s += part[i][tid];
    scores[tid] = s;
  }
  __syncthreads();
  if (tid < 2) {
    const int base = tid * 8;
    float mx = scores[base];
    for (int t = 1; t < 8; ++t) mx = fmaxf(mx, scores[base + t]);
    float sum = 0.f;
    float e[8];
    for (int t = 0; t < 8; ++t) { e[t] = __expf(scores[base + t] - mx); sum += e[t]; }
    float inv = 1.f / sum;
    for (int t = 0; t < 8; ++t) alpha[base + t] = e[t] * inv;
  }
  __syncthreads();

  float* efb = EF + (size_t)b * 4096;
  for (int h = tid; h < 1024; h += 256) {
    float l1 = 0.f, l2 = 0.f;
#pragma unroll
    for (int t = 0; t < 8; ++t) {
      float c = ld1<BF16>(temb, t * 1024 + h);
      l1 += alpha[t] * c;
      l2 += alpha[8 + t] * c;
    }
    efb[h] = eh1[h];
    efb[1024 + h] = l1;
    efb[2048 + h] = eh2[h];
    efb[3072 + h] = l2;
  }
}

// ---------------------------------------------------------------------------
// Kernel E2: dense_ent partials = EF[64,4096] @ W_ent[4096,512], k-split 8.
// grid 32 = kb(8) * nb(4); block 256. Block: m 0..63, n-chunk 128, k-chunk 512.
// Thread: 8 m x 4 n register tile. part[8][64][512] fp32, no atomics.
// ---------------------------------------------------------------------------
template <bool BF16>
__global__ __launch_bounds__(256) void ent_gemm(const float* __restrict__ EF,
                                                const void* __restrict__ went,
                                                float* __restrict__ part,
                                                const int* __restrict__ flag) {
  if ((*flag != 0) != BF16) return;
  const int nb = blockIdx.x & 3;
  const int kb = blockIdx.x >> 2;  // 0..7
  const int tid = threadIdx.x;
  __shared__ float efs[64][64];  // 16 KB

  const int n0 = nb * 128 + (tid & 31) * 4;
  const int mg = (tid >> 5) * 8;
  float acc[8][4];
#pragma unroll
  for (int i = 0; i < 8; ++i)
#pragma unroll
    for (int j = 0; j < 4; ++j) acc[i][j] = 0.f;

  for (int kk = 0; kk < 8; ++kk) {
    const int k0 = kb * 512 + kk * 64;
    __syncthreads();
    {  // stage EF[0:64][k0:k0+64]
      const int kq = (tid & 15) * 4;
      for (int m = tid >> 4; m < 64; m += 16) {
        *(float4*)&efs[m][kq] = *(const float4*)&EF[(size_t)m * 4096 + k0 + kq];
      }
    }
    __syncthreads();
    for (int k = 0; k < 64; ++k) {
      float4 w = ld4<BF16>(went, (size_t)(k0 + k) * A_ + n0);
#pragma unroll
      for (int i = 0; i < 8; ++i) {
        float e = efs[mg + i][k];
        acc[i][0] += e * w.x;
        acc[i][1] += e * w.y;
        acc[i][2] += e * w.z;
        acc[i][3] += e * w.w;
      }
    }
  }
#pragma unroll
  for (int i = 0; i < 8; ++i) {
    *(float4*)&part[((size_t)kb * 64 + mg + i) * A_ + n0] =
        (float4){acc[i][0], acc[i][1], acc[i][2], acc[i][3]};
  }
}

// ---------------------------------------------------------------------------
// Kernel E3: dense_ent[64][512] = sum over 8 k-chunks of part. grid 128.
// ---------------------------------------------------------------------------
__global__ __launch_bounds__(256) void ent_reduce(const float* __restrict__ part,
                                                  float* __restrict__ dense_ent) {
  const int idx = blockIdx.x * 256 + threadIdx.x;  // 0..32767
  float s = 0.f;
#pragma unroll
  for (int kb = 0; kb < 8; ++kb) s += part[(size_t)kb * 32768 + idx];
  dense_ent[idx] = s;
}

// ---------------------------------------------------------------------------
// Kernel 4: fused MFMA GEMM  u = tanh(pos_features @ W_pos + ent)  -> vu = u @ v
// ROUND-4 STRUCTURE, M-SPLIT ONLY: BM=32 (was 64), BN=512 (full), BK=32.
// grid 512 (2 blocks/CU), block 512 (8 waves; wave w covers n in [64w, 64w+64)).
// Single-buffer LDS + per-step barrier exactly as round 4; A tile halves
// (mf loop 0..1, staged by tid<256). Everything else byte-equivalent.
// dense_ent_r[b,l,a] = dense_ent[b, 2l + (a>=256)]  (the tf.repeat interleave).
// ---------------------------------------------------------------------------
template <bool BF16>
__global__ __launch_bounds__(512) void fused_gemm_vu(
    const void* __restrict__ wh, const void* __restrict__ pe1,
    const void* __restrict__ pe2, const ushort* __restrict__ WT,
    const float* __restrict__ dense_ent, const void* __restrict__ vvec,
    float* __restrict__ vu, const int* __restrict__ flag) {
  if ((*flag != 0) != BF16) return;
  // stride 40 ushort (80 B) rows: conflict-free ds_read_b128 (round-4 layout)
  __shared__ __align__(16) ushort Atile[32 * 40];
  __shared__ __align__(16) ushort Btile[512 * 40];
  __shared__ float vu_w[8][32];

  const int tid = threadIdx.x;
  const int rbase = blockIdx.x * 32;
  const int lane = tid & 63;
  const int wave = tid >> 6;
  const int quad = lane >> 4;
  const int col = lane & 15;

  f32x4 acc[2][4];
#pragma unroll
  for (int i = 0; i < 2; ++i)
#pragma unroll
    for (int j = 0; j < 4; ++j) acc[i][j] = (f32x4){0.f, 0.f, 0.f, 0.f};

  const int arow = tid >> 3;         // 0..31 for tid<256
  const int akq = (tid & 7) * 4;     // 0,4,...,28

  for (int step = 0; step < 36; ++step) {
    const void* srcA;
    int ldA, k0A;
    if (step < 32)      { srcA = wh;  ldA = H_; k0A = step * 32; }
    else if (step < 34) { srcA = pe1; ldA = P_; k0A = (step - 32) * 32; }
    else                { srcA = pe2; ldA = P_; k0A = (step - 34) * 32; }

    if (step) __syncthreads();
    if (tid < 256) {  // A tile: 32 rows x 32 k, 4 elements per thread
      const size_t off = (size_t)(rbase + arow) * ldA + k0A + akq;
      if (BF16) {
        *(ushort4*)&Atile[arow * 40 + akq] = *(const ushort4*)((const ushort*)srcA + off);
      } else {
        float4 f = *(const float4*)((const float*)srcA + off);
        uint2 pk;
        pk.x = pack2_rne(f.x, f.y);
        pk.y = pack2_rne(f.z, f.w);
        *(uint2*)&Atile[arow * 40 + akq] = pk;
      }
    }
    {  // B tile (always bf16): 512 rows x 32 k = 64 B per thread (4x uint4)
      const ushort* s = WT + (size_t)tid * KDIM + step * 32;
      uint4 v0 = *(const uint4*)(s + 0);    // ushorts 0..7
      uint4 v1 = *(const uint4*)(s + 8);    // ushorts 8..15
      uint4 v2 = *(const uint4*)(s + 16);   // ushorts 16..23
      uint4 v3 = *(const uint4*)(s + 24);   // ushorts 24..31
      ushort* d = &Btile[tid * 40];
      *(uint4*)(d + 0)  = v0;
      *(uint4*)(d + 8)  = v1;
      *(uint4*)(d + 16) = v2;
      *(uint4*)(d + 24) = v3;
    }
    __syncthreads();

    bf16x8 af[2], bfr[4];
#pragma unroll
    for (int mf = 0; mf < 2; ++mf)
      af[mf] = *(const bf16x8*)&Atile[(mf * 16 + col) * 40 + quad * 8];
#pragma unroll
    for (int nf = 0; nf < 4; ++nf)
      bfr[nf] = *(const bf16x8*)&Btile[(wave * 64 + nf * 16 + col) * 40 + quad * 8];
#pragma unroll
    for (int mf = 0; mf < 2; ++mf)
#pragma unroll
      for (int nf = 0; nf < 4; ++nf)
        acc[mf][nf] = __builtin_amdgcn_mfma_f32_16x16x32_bf16(af[mf], bfr[nf], acc[mf][nf], 0, 0, 0);
  }

  // Epilogue: C/D layout col=lane&15 (n), row=quad*4+reg (m). Wave's 64 n are all
  // on one side of 256, so 'side' is wave-uniform.
  const int nbase = wave * 64;
  const int side = (nbase >= 256) ? 1 : 0;
  float vv[4];
#pragma unroll
  for (int nf = 0; nf < 4; ++nf) vv[nf] = ld1<BF16>(vvec, nbase + nf * 16 + col);

#pragma unroll
  for (int mf = 0; mf < 2; ++mf) {
    const int row0 = mf * 16 + quad * 4;
    const int r0 = rbase + row0;
    const int bidx = r0 >> 8;
    const int l0 = r0 & 255;
    const float* ebase = dense_ent + bidx * A_ + 2 * l0 + side;
    float e0 = ebase[0], e1 = ebase[2], e2 = ebase[4], e3 = ebase[6];
    float s0 = 0.f, s1 = 0.f, s2 = 0.f, s3 = 0.f;
#pragma unroll
    for (int nf = 0; nf < 4; ++nf) {
      float vn = vv[nf];
      s0 += tanhf(acc[mf][nf][0] + e0) * vn;
      s1 += tanhf(acc[mf][nf][1] + e1) * vn;
      s2 += tanhf(acc[mf][nf][2] + e2) * vn;
      s3 += tanhf(acc[mf][nf][3] + e3) * vn;
    }
    // reduce over the 16 col lanes (xor<16 stays within the quad)
    s0 += __shfl_xor(s0, 1); s0 += __shfl_xor(s0, 2); s0 += __shfl_xor(s0, 4); s0 += __shfl_xor(s0, 8);
    s1 += __shfl_xor(s1, 1); s1 += __shfl_xor(s1, 2); s1 += __shfl_xor(s1, 4); s1 += __shfl_xor(s1, 8);
    s2 += __shfl_xor(s2, 1); s2 += __shfl_xor(s2, 2); s2 += __shfl_xor(s2, 4); s2 += __shfl_xor(s2, 8);
    s3 += __shfl_xor(s3, 1); s3 += __shfl_xor(s3, 2); s3 += __shfl_xor(s3, 4); s3 += __shfl_xor(s3, 8);
    if (col == 0) {
      vu_w[wave][row0 + 0] = s0;
      vu_w[wave][row0 + 1] = s1;
      vu_w[wave][row0 + 2] = s2;
      vu_w[wave][row0 + 3] = s3;
    }
  }
  __syncthreads();
  if (tid < 32) {
    float s = 0.f;
#pragma unroll
    for (int w = 0; w < 8; ++w) s += vu_w[w][tid];
    vu[rbase + tid] = s;
  }
}

// ---------------------------------------------------------------------------
// Kernel 5: per-b softmax over L, then z[b,h] = sum_l alpha[l] * wh[b,l,h]
// grid 256 = b*4 + hq, block 256. Output dtype matches input dtype.
// ---------------------------------------------------------------------------
template <bool BF16>
__global__ __launch_bounds__(256) void softmax_z(const void* __restrict__ wh,
                                                 const float* __restrict__ vu,
                                                 void* __restrict__ out,
                                                 const int* __restrict__ flag) {
  if ((*flag != 0) != BF16) return;
  const int b = blockIdx.x >> 2;
  const int hq = blockIdx.x & 3;
  const int tid = threadIdx.x;
  __shared__ float alpha[256];
  __shared__ float red[256];

  float x = vu[b * L_ + tid];
  red[tid] = x;
  __syncthreads();
  for (int s = 128; s > 0; s >>= 1) {
    if (tid < s) red[tid] = fmaxf(red[tid], red[tid + s]);
    __syncthreads();
  }
  float m = red[0];
  __syncthreads();
  float e = __expf(x - m);
  red[tid] = e;
  __syncthreads();
  for (int s = 128; s > 0; s >>= 1) {
    if (tid < s) red[tid] += red[tid + s];
    __syncthreads();
  }
  alpha[tid] = e / red[0];
  __syncthreads();

  const int h = hq * 256 + tid;
  const size_t base = (size_t)b * L_ * H_ + h;
  float a0 = 0.f, a1 = 0.f, a2 = 0.f, a3 = 0.f;
  for (int l = 0; l < 256; l += 4) {
    a0 += alpha[l + 0] * ld1<BF16>(wh, base + (size_t)(l + 0) * H_);
    a1 += alpha[l + 1] * ld1<BF16>(wh, base + (size_t)(l + 1) * H_);
    a2 += alpha[l + 2] * ld1<BF16>(wh, base + (size_t)(l + 2) * H_);
    a3 += alpha[l + 3] * ld1<BF16>(wh, base + (size_t)(l + 3) * H_);
  }
  float z = (a0 + a1) + (a2 + a3);
  if (BF16) ((ushort*)out)[b * H_ + h] = f2bf_rne(z);
  else ((float*)out)[b * H_ + h] = z;
}

// ---------------------------------------------------------------------------
extern "C" void kernel_launch(void* const* d_in, const int* in_sizes, int n_in,
                              void* d_out, int out_size, void* d_ws, size_t ws_size,
                              hipStream_t stream) {
  const void* wh   = d_in[0];               // word_hiddens [64,256,1024]
  const void* pe1  = d_in[1];               // pos_e1 [64,256,64]
  const void* pe2  = d_in[2];               // pos_e2 [64,256,64]
  const int*  e1e  = (const int*)d_in[3];   // [64] i32
  const int*  e2e  = (const int*)d_in[4];   // [64] i32
  const void* temb = d_in[5];               // type_embeddings [8,1024]
  const void* wpos = d_in[6];               // W_pos [1152,512]
  const void* went = d_in[7];               // W_ent [4096,512]
  const void* vvec = d_in[8];               // v [512]

  char* ws = (char*)d_ws;
  int*   flag      = (int*)ws;                          // 256 B slot
  ushort* WT       = (ushort*)(ws + 256);               // 1179648 B
  float* dense_ent = (float*)(ws + 256 + 1179648);      // 131072 B
  float* vu        = (float*)(ws + 256 + 1310720);      // 65536 B
  float* EF        = (float*)(ws + 256 + 1376256);      // 1048576 B
  float* part      = (float*)(ws + 256 + 2424832);      // 1048576 B  (total ~3.5 MB)

  detect_dtype<<<dim3(1), dim3(256), 0, stream>>>((const ushort*)wh, flag);

  transpose_wpos<true ><<<dim3(576), dim3(256), 0, stream>>>(wpos, WT, flag);
  transpose_wpos<false><<<dim3(576), dim3(256), 0, stream>>>(wpos, WT, flag);

  entity_features_k<true ><<<dim3(64), dim3(256), 0, stream>>>(wh, e1e, e2e, temb, EF, flag);
  entity_features_k<false><<<dim3(64), dim3(256), 0, stream>>>(wh, e1e, e2e, temb, EF, flag);

  ent_gemm<true ><<<dim3(32), dim3(256), 0, stream>>>(EF, went, part, flag);
  ent_gemm<false><<<dim3(32), dim3(256), 0, stream>>>(EF, went, part, flag);

  ent_reduce<<<dim3(128), dim3(256), 0, stream>>>(part, dense_ent);

  fused_gemm_vu<true ><<<dim3(512), dim3(512), 0, stream>>>(wh, pe1, pe2, WT, dense_ent, vvec, vu, flag);
  fused_gemm_vu<false><<<dim3(512), dim3(512), 0, stream>>>(wh, pe1, pe2, WT, dense_ent, vvec, vu, flag);

  softmax_z<true ><<<dim3(256), dim3(256), 0, stream>>>(wh, vu, d_out, flag);
  softmax_z<false><<<dim3(256), dim3(256), 0, stream>>>(wh, vu, d_out, flag);
}

// Round 9
// 220.210 us; speedup vs baseline: 1.3445x; 1.3445x over previous
//
#include <hip/hip_runtime.h>
#include <hip/hip_bf16.h>
#include <math.h>

// Problem constants
#define B_ 64
#define L_ 256
#define H_ 1024
#define P_ 64
#define A_ 512
#define T_ 8
#define KDIM 1152  // H + 2P
#define NSTEP 36

typedef __attribute__((ext_vector_type(8))) __bf16 bf16x8;
typedef __attribute__((ext_vector_type(4))) float f32x4;

__device__ __forceinline__ float bf2f(ushort u) {
  union { unsigned int i; float f; } v; v.i = ((unsigned int)u) << 16; return v.f;
}
__device__ __forceinline__ ushort f2bf_rne(float f) {
  union { float f; unsigned int i; } v; v.f = f;
  unsigned int r = v.i + 0x7FFFu + ((v.i >> 16) & 1u);  // RNE
  return (ushort)(r >> 16);
}
__device__ __forceinline__ unsigned int pack2_rne(float a, float b) {
  return (unsigned int)f2bf_rne(a) | ((unsigned int)f2bf_rne(b) << 16);
}

// scalar load: element i of a buffer that is bf16 if BF16 else fp32
template <bool BF16>
__device__ __forceinline__ float ld1(const void* p, size_t i) {
  if (BF16) return bf2f(((const ushort*)p)[i]);
  return ((const float*)p)[i];
}
// 4-wide load, i must be a multiple of 4
template <bool BF16>
__device__ __forceinline__ float4 ld4(const void* p, size_t i) {
  if (BF16) {
    ushort4 u = *(const ushort4*)((const ushort*)p + i);
    return (float4){bf2f(u.x), bf2f(u.y), bf2f(u.z), bf2f(u.w)};
  }
  return *(const float4*)((const float*)p + i);
}

// ---------------------------------------------------------------------------
// Kernel 0: dtype detector (unchanged from round 8 — proven).
// ---------------------------------------------------------------------------
__global__ __launch_bounds__(256) void detect_dtype(const ushort* __restrict__ wh,
                                                    int* __restrict__ flag) {
  __shared__ int cnt;
  if (threadIdx.x == 0) cnt = 0;
  __syncthreads();
  int c = 0;
  for (int i = threadIdx.x; i < 8192; i += 256) {
    int e = (wh[i] >> 7) & 0xFF;
    if (e >= 110 && e <= 135) c++;
  }
  atomicAdd(&cnt, c);
  __syncthreads();
  if (threadIdx.x == 0) flag[0] = (cnt > 6553) ? 1 : 0;  // >80% plausible -> bf16
}

// ---------------------------------------------------------------------------
// Kernel 1: W_pos [1152][512] -> step-tiled WTs[36][512][32] bf16.
// WTs[s][n][k2] = W_pos[s*32+k2][n]. Per-step B is a contiguous 32KB chunk
// (16KB per 256-row n-half) -> perfectly coalesced GEMM staging.
// grid 576 = 36 steps x 16 n-tiles, block 256 (32x8).
// ---------------------------------------------------------------------------
template <bool BF16>
__global__ __launch_bounds__(256) void build_wts(const void* __restrict__ W,
                                                 ushort* __restrict__ WTs,
                                                 const int* __restrict__ flag) {
  if ((*flag != 0) != BF16) return;
  __shared__ ushort tile[32][33];
  const int s  = blockIdx.x >> 4;   // 0..35 (k-step)
  const int at = blockIdx.x & 15;   // 0..15 (n tile of 32)
  const int tx = threadIdx.x & 31;
  const int ty = threadIdx.x >> 5;  // 0..7
#pragma unroll
  for (int i = 0; i < 4; ++i) {
    size_t idx = (size_t)(s * 32 + ty + i * 8) * A_ + at * 32 + tx;
    ushort u;
    if (BF16) u = ((const ushort*)W)[idx];
    else u = f2bf_rne(((const float*)W)[idx]);
    tile[ty + i * 8][tx] = u;
  }
  __syncthreads();
#pragma unroll
  for (int i = 0; i < 4; ++i) {
    // WTs[s][n = at*32+ty+i*8][k2 = tx] = W_pos[s*32+tx][n]
    WTs[(size_t)s * (A_ * 32) + (size_t)(at * 32 + ty + i * 8) * 32 + tx] =
        tile[tx][ty + i * 8];
  }
}

// ---------------------------------------------------------------------------
// Kernel E1: entity features EF[64][4096] fp32 (unchanged from round 8).
// ---------------------------------------------------------------------------
template <bool BF16>
__global__ __launch_bounds__(256) void entity_features_k(
    const void* __restrict__ wh, const int* __restrict__ e1e,
    const int* __restrict__ e2e, const void* __restrict__ temb,
    float* __restrict__ EF, const int* __restrict__ flag) {
  if ((*flag != 0) != BF16) return;
  const int b = blockIdx.x;
  const int tid = threadIdx.x;
  __shared__ float eh1[1024];
  __shared__ float eh2[1024];
  __shared__ float part[256][16];
  __shared__ float scores[16];
  __shared__ float alpha[16];

  const size_t o1 = ((size_t)b * L_ + e1e[b]) * H_;
  const size_t o2 = ((size_t)b * L_ + e2e[b]) * H_;
  for (int h = tid; h < 1024; h += 256) {
    eh1[h] = ld1<BF16>(wh, o1 + h);
    eh2[h] = ld1<BF16>(wh, o2 + h);
  }
  __syncthreads();

  float p[16];
#pragma unroll
  for (int t = 0; t < 16; ++t) p[t] = 0.f;
  for (int h = tid; h < 1024; h += 256) {
    float a1 = eh1[h], a2 = eh2[h];
#pragma unroll
    for (int t = 0; t < 8; ++t) {
      float c = ld1<BF16>(temb, t * 1024 + h);
      p[t] += a1 * c;
      p[8 + t] += a2 * c;
    }
  }
#pragma unroll
  for (int t = 0; t < 16; ++t) part[tid][t] = p[t];
  __syncthreads();
  if (tid < 16) {
    float s = 0.f;
    for (int i = 0; i < 256; ++i) s += part[i][tid];
    scores[tid] = s;
  }
  __syncthreads();
  if (tid < 2) {
    const int base = tid * 8;
    float mx = scores[base];
    for (int t = 1; t < 8; ++t) mx = fmaxf(mx, scores[base + t]);
    float sum = 0.f;
    float e[8];
    for (int t = 0; t < 8; ++t) { e[t] = __expf(scores[base + t] - mx); sum += e[t]; }
    float inv = 1.f / sum;
    for (int t = 0; t < 8; ++t) alpha[base + t] = e[t] * inv;
  }
  __syncthreads();

  float* efb = EF + (size_t)b * 4096;
  for (int h = tid; h < 1024; h += 256) {
    float l1 = 0.f, l2 = 0.f;
#pragma unroll
    for (int t = 0; t < 8; ++t) {
      float c = ld1<BF16>(temb, t * 1024 + h);
      l1 += alpha[t] * c;
      l2 += alpha[8 + t] * c;
    }
    efb[h] = eh1[h];
    efb[1024 + h] = l1;
    efb[2048 + h] = eh2[h];
    efb[3072 + h] = l2;
  }
}

// ---------------------------------------------------------------------------
// Kernel E2: dense_ent partials = EF[64,4096] @ W_ent[4096,512], k-split 32.
// grid 128 = kb(32)*nb(4); block 256. One 128-k chunk per block (round-4 body
// pattern: same staging style, same compute loop, same store).
// Thread: 8m x 4n register tile. part[32][64][512] fp32, deterministic.
// ---------------------------------------------------------------------------
template <bool BF16>
__global__ __launch_bounds__(256) void ent_gemm(const float* __restrict__ EF,
                                                const void* __restrict__ went,
                                                float* __restrict__ part,
                                                const int* __restrict__ flag) {
  if ((*flag != 0) != BF16) return;
  const int nb = blockIdx.x & 3;
  const int kb = blockIdx.x >> 2;  // 0..31
  const int tid = threadIdx.x;
  __shared__ float efs[64][128];   // 32 KB

  const int k0 = kb * 128;
  {  // stage EF[0:64][k0:k0+128): 8 x float4 per thread, coalesced
    const int kq = (tid & 31) * 4;
    for (int m = tid >> 5; m < 64; m += 8) {
      *(float4*)&efs[m][kq] = *(const float4*)&EF[(size_t)m * 4096 + k0 + kq];
    }
  }
  __syncthreads();

  const int n0 = nb * 128 + (tid & 31) * 4;
  const int mg = (tid >> 5) * 8;
  float acc[8][4];
#pragma unroll
  for (int i = 0; i < 8; ++i)
#pragma unroll
    for (int j = 0; j < 4; ++j) acc[i][j] = 0.f;

  for (int k = 0; k < 128; ++k) {
    float4 w = ld4<BF16>(went, (size_t)(k0 + k) * A_ + n0);
#pragma unroll
    for (int i = 0; i < 8; ++i) {
      float e = efs[mg + i][k];
      acc[i][0] += e * w.x;
      acc[i][1] += e * w.y;
      acc[i][2] += e * w.z;
      acc[i][3] += e * w.w;
    }
  }
#pragma unroll
  for (int i = 0; i < 8; ++i) {
    *(float4*)&part[((size_t)kb * 64 + mg + i) * A_ + n0] =
        (float4){acc[i][0], acc[i][1], acc[i][2], acc[i][3]};
  }
}

// ---------------------------------------------------------------------------
// Kernel E3: dense_ent[64][512] = sum over 32 k-chunks of part. grid 128.
// ---------------------------------------------------------------------------
__global__ __launch_bounds__(256) void ent_reduce(const float* __restrict__ part,
                                                  float* __restrict__ dense_ent) {
  const int idx = blockIdx.x * 256 + threadIdx.x;  // 0..32767
  float s = 0.f;
#pragma unroll
  for (int kb = 0; kb < 32; ++kb) s += part[(size_t)kb * 32768 + idx];
  dense_ent[idx] = s;
}

// ---------------------------------------------------------------------------
// Kernel 4: fused MFMA GEMM  u = tanh(pos_features @ W_pos + ent) -> vu = u @ v
// BM=64, BN=256, BK=32. grid 512 = mb(256) x nb(2) -> 2 blocks/CU.
// block 256 (4 waves; wave w covers n-local [64w, 64w+64)).
// Register-prefetch double-buffered LDS (load s+1 during MFMA of s), one
// barrier per step. B staged from step-tiled WTs: 64 B/thread contiguous,
// perfectly coalesced. LDS rows stride 40 ushorts (proven conflict profile).
// dense_ent_r[b,l,a] = dense_ent[b, 2l + (a>=256)]; side == nb (wave-uniform).
// Writes vu_part[nb][16384] fp32 (deterministic, summed in softmax_z).
// ---------------------------------------------------------------------------
template <bool BF16>
__global__ __launch_bounds__(256) void fused_gemm_vu(
    const void* __restrict__ wh, const void* __restrict__ pe1,
    const void* __restrict__ pe2, const ushort* __restrict__ WTs,
    const float* __restrict__ dense_ent, const void* __restrict__ vvec,
    float* __restrict__ vu_part, const int* __restrict__ flag) {
  if ((*flag != 0) != BF16) return;
  __shared__ __align__(16) ushort Abuf[2][64 * 40];    // 5120 B each
  __shared__ __align__(16) ushort Bbuf[2][256 * 40];   // 20480 B each
  __shared__ float vu_s[4][64];

  const int tid = threadIdx.x;
  const int nb = blockIdx.x & 1;
  const int mb = blockIdx.x >> 1;       // 0..255
  const int rbase = mb * 64;
  const int wave = tid >> 6;            // 0..3
  const int lane = tid & 63;
  const int quad = lane >> 4;
  const int col = lane & 15;

  // A staging: 64 rows x 32 k; thread -> (row = tid>>2, kq = (tid&3)*8)
  const int arow = tid >> 2;
  const int akq = (tid & 3) * 8;
  const int myrow = rbase + arow;
  // B staging: row n-local = tid, 32 ushorts (64 B) contiguous from WTs
  const ushort* bbase = WTs + (size_t)nb * (256 * 32) + (size_t)tid * 32;

  f32x4 acc[4][4];
#pragma unroll
  for (int i = 0; i < 4; ++i)
#pragma unroll
    for (int j = 0; j < 4; ++j) acc[i][j] = (f32x4){0.f, 0.f, 0.f, 0.f};

  uint4 aR, bR0, bR1;

  // ---- prefetch step 0 into registers ----
  {
    const size_t off = (size_t)myrow * H_ + 0 * 32 + akq;  // step 0 is wh
    if (BF16) {
      aR = *(const uint4*)((const ushort*)wh + off);
    } else {
      float4 f0 = *(const float4*)((const float*)wh + off);
      float4 f1 = *(const float4*)((const float*)wh + off + 4);
      aR.x = pack2_rne(f0.x, f0.y); aR.y = pack2_rne(f0.z, f0.w);
      aR.z = pack2_rne(f1.x, f1.y); aR.w = pack2_rne(f1.z, f1.w);
    }
    const ushort* bs = bbase;  // + 0 * 512 * 32
    bR0 = *(const uint4*)(bs + 0);
    bR1 = *(const uint4*)(bs + 8);
  }
  uint4 bR2 = *(const uint4*)(bbase + 16);
  uint4 bR3 = *(const uint4*)(bbase + 24);
  // ---- store step 0 to buffer 0 ----
  {
    *(uint4*)&Abuf[0][arow * 40 + akq] = aR;
    ushort* bd = &Bbuf[0][tid * 40];
    *(uint4*)(bd + 0)  = bR0;
    *(uint4*)(bd + 8)  = bR1;
    *(uint4*)(bd + 16) = bR2;
    *(uint4*)(bd + 24) = bR3;
  }
  __syncthreads();

  for (int s = 0; s < NSTEP; ++s) {
    const int cur = s & 1;

    // prefetch step s+1 into registers (loads issue; waited at the LDS store)
    if (s < NSTEP - 1) {
      const int sn = s + 1;
      const void* srcA;
      int ldA, k0A;
      if (sn < 32)      { srcA = wh;  ldA = H_; k0A = sn * 32; }
      else if (sn < 34) { srcA = pe1; ldA = P_; k0A = (sn - 32) * 32; }
      else              { srcA = pe2; ldA = P_; k0A = (sn - 34) * 32; }
      const size_t off = (size_t)myrow * ldA + k0A + akq;
      if (BF16) {
        aR = *(const uint4*)((const ushort*)srcA + off);
      } else {
        float4 f0 = *(const float4*)((const float*)srcA + off);
        float4 f1 = *(const float4*)((const float*)srcA + off + 4);
        aR.x = pack2_rne(f0.x, f0.y); aR.y = pack2_rne(f0.z, f0.w);
        aR.z = pack2_rne(f1.x, f1.y); aR.w = pack2_rne(f1.z, f1.w);
      }
      const ushort* bs = bbase + (size_t)sn * (A_ * 32);
      bR0 = *(const uint4*)(bs + 0);
      bR1 = *(const uint4*)(bs + 8);
      bR2 = *(const uint4*)(bs + 16);
      bR3 = *(const uint4*)(bs + 24);
    }

    // MFMA on current buffer
    bf16x8 af[4], bfr[4];
#pragma unroll
    for (int mf = 0; mf < 4; ++mf)
      af[mf] = *(const bf16x8*)&Abuf[cur][(mf * 16 + col) * 40 + quad * 8];
#pragma unroll
    for (int nf = 0; nf < 4; ++nf)
      bfr[nf] = *(const bf16x8*)&Bbuf[cur][(wave * 64 + nf * 16 + col) * 40 + quad * 8];
#pragma unroll
    for (int mf = 0; mf < 4; ++mf)
#pragma unroll
      for (int nf = 0; nf < 4; ++nf)
        acc[mf][nf] = __builtin_amdgcn_mfma_f32_16x16x32_bf16(af[mf], bfr[nf], acc[mf][nf], 0, 0, 0);

    // store prefetched step into the other buffer, then barrier
    if (s < NSTEP - 1) {
      const int nxt = cur ^ 1;
      *(uint4*)&Abuf[nxt][arow * 40 + akq] = aR;
      ushort* bd = &Bbuf[nxt][tid * 40];
      *(uint4*)(bd + 0)  = bR0;
      *(uint4*)(bd + 8)  = bR1;
      *(uint4*)(bd + 16) = bR2;
      *(uint4*)(bd + 24) = bR3;
      __syncthreads();
    }
  }

  // Epilogue: C/D layout col=lane&15 (n), row=quad*4+reg (m). side = nb.
  float vv[4];
#pragma unroll
  for (int nf = 0; nf < 4; ++nf)
    vv[nf] = ld1<BF16>(vvec, nb * 256 + wave * 64 + nf * 16 + col);

#pragma unroll
  for (int mf = 0; mf < 4; ++mf) {
    const int row0 = mf * 16 + quad * 4;
    const int r0 = rbase + row0;
    const int bidx = r0 >> 8;
    const int l0 = r0 & 255;
    const float* ebase = dense_ent + bidx * A_ + 2 * l0 + nb;
    float e0 = ebase[0], e1 = ebase[2], e2 = ebase[4], e3 = ebase[6];
    float s0 = 0.f, s1 = 0.f, s2 = 0.f, s3 = 0.f;
#pragma unroll
    for (int nf = 0; nf < 4; ++nf) {
      float vn = vv[nf];
      s0 += tanhf(acc[mf][nf][0] + e0) * vn;
      s1 += tanhf(acc[mf][nf][1] + e1) * vn;
      s2 += tanhf(acc[mf][nf][2] + e2) * vn;
      s3 += tanhf(acc[mf][nf][3] + e3) * vn;
    }
    // reduce over the 16 col lanes (xor<16 stays within the quad)
    s0 += __shfl_xor(s0, 1); s0 += __shfl_xor(s0, 2); s0 += __shfl_xor(s0, 4); s0 += __shfl_xor(s0, 8);
    s1 += __shfl_xor(s1, 1); s1 += __shfl_xor(s1, 2); s1 += __shfl_xor(s1, 4); s1 += __shfl_xor(s1, 8);
    s2 += __shfl_xor(s2, 1); s2 += __shfl_xor(s2, 2); s2 += __shfl_xor(s2, 4); s2 += __shfl_xor(s2, 8);
    s3 += __shfl_xor(s3, 1); s3 += __shfl_xor(s3, 2); s3 += __shfl_xor(s3, 4); s3 += __shfl_xor(s3, 8);
    if (col == 0) {
      vu_s[wave][row0 + 0] = s0;
      vu_s[wave][row0 + 1] = s1;
      vu_s[wave][row0 + 2] = s2;
      vu_s[wave][row0 + 3] = s3;
    }
  }
  __syncthreads();
  if (tid < 64) {
    float s = vu_s[0][tid] + vu_s[1][tid] + vu_s[2][tid] + vu_s[3][tid];
    vu_part[(size_t)nb * (B_ * L_) + rbase + tid] = s;
  }
}

// ---------------------------------------------------------------------------
// Kernel 5: per-b softmax over L, then z[b,h] = sum_l alpha[l] * wh[b,l,h]
// grid 256 = b*4 + hq, block 256. Sums the two n-partials of vu.
// ---------------------------------------------------------------------------
template <bool BF16>
__global__ __launch_bounds__(256) void softmax_z(const void* __restrict__ wh,
                                                 const float* __restrict__ vu_part,
                                                 void* __restrict__ out,
                                                 const int* __restrict__ flag) {
  if ((*flag != 0) != BF16) return;
  const int b = blockIdx.x >> 2;
  const int hq = blockIdx.x & 3;
  const int tid = threadIdx.x;
  __shared__ float alpha[256];
  __shared__ float red[256];

  float x = vu_part[b * L_ + tid] + vu_part[B_ * L_ + b * L_ + tid];
  red[tid] = x;
  __syncthreads();
  for (int s = 128; s > 0; s >>= 1) {
    if (tid < s) red[tid] = fmaxf(red[tid], red[tid + s]);
    __syncthreads();
  }
  float m = red[0];
  __syncthreads();
  float e = __expf(x - m);
  red[tid] = e;
  __syncthreads();
  for (int s = 128; s > 0; s >>= 1) {
    if (tid < s) red[tid] += red[tid + s];
    __syncthreads();
  }
  alpha[tid] = e / red[0];
  __syncthreads();

  const int h = hq * 256 + tid;
  const size_t base = (size_t)b * L_ * H_ + h;
  float a0 = 0.f, a1 = 0.f, a2 = 0.f, a3 = 0.f;
  for (int l = 0; l < 256; l += 4) {
    a0 += alpha[l + 0] * ld1<BF16>(wh, base + (size_t)(l + 0) * H_);
    a1 += alpha[l + 1] * ld1<BF16>(wh, base + (size_t)(l + 1) * H_);
    a2 += alpha[l + 2] * ld1<BF16>(wh, base + (size_t)(l + 2) * H_);
    a3 += alpha[l + 3] * ld1<BF16>(wh, base + (size_t)(l + 3) * H_);
  }
  float z = (a0 + a1) + (a2 + a3);
  if (BF16) ((ushort*)out)[b * H_ + h] = f2bf_rne(z);
  else ((float*)out)[b * H_ + h] = z;
}

// ---------------------------------------------------------------------------
extern "C" void kernel_launch(void* const* d_in, const int* in_sizes, int n_in,
                              void* d_out, int out_size, void* d_ws, size_t ws_size,
                              hipStream_t stream) {
  const void* wh   = d_in[0];               // word_hiddens [64,256,1024]
  const void* pe1  = d_in[1];               // pos_e1 [64,256,64]
  const void* pe2  = d_in[2];               // pos_e2 [64,256,64]
  const int*  e1e  = (const int*)d_in[3];   // [64] i32
  const int*  e2e  = (const int*)d_in[4];   // [64] i32
  const void* temb = d_in[5];               // type_embeddings [8,1024]
  const void* wpos = d_in[6];               // W_pos [1152,512]
  const void* went = d_in[7];               // W_ent [4096,512]
  const void* vvec = d_in[8];               // v [512]

  char* ws = (char*)d_ws;
  int*   flag      = (int*)ws;                     // 256 B slot
  ushort* WTs      = (ushort*)(ws + 256);          // 1179648 B
  float* dense_ent = (float*)(ws + 1179904);       // 131072 B
  float* vu_part   = (float*)(ws + 1310976);       // 131072 B (2 partials)
  float* EF        = (float*)(ws + 1442048);       // 1048576 B
  float* part      = (float*)(ws + 2490624);       // 4194304 B (total ~6.7 MB)

  detect_dtype<<<dim3(1), dim3(256), 0, stream>>>((const ushort*)wh, flag);

  build_wts<true ><<<dim3(576), dim3(256), 0, stream>>>(wpos, WTs, flag);
  build_wts<false><<<dim3(576), dim3(256), 0, stream>>>(wpos, WTs, flag);

  entity_features_k<true ><<<dim3(64), dim3(256), 0, stream>>>(wh, e1e, e2e, temb, EF, flag);
  entity_features_k<false><<<dim3(64), dim3(256), 0, stream>>>(wh, e1e, e2e, temb, EF, flag);

  ent_gemm<true ><<<dim3(128), dim3(256), 0, stream>>>(EF, went, part, flag);
  ent_gemm<false><<<dim3(128), dim3(256), 0, stream>>>(EF, went, part, flag);

  ent_reduce<<<dim3(128), dim3(256), 0, stream>>>(part, dense_ent);

  fused_gemm_vu<true ><<<dim3(512), dim3(256), 0, stream>>>(wh, pe1, pe2, WTs, dense_ent, vvec, vu_part, flag);
  fused_gemm_vu<false><<<dim3(512), dim3(256), 0, stream>>>(wh, pe1, pe2, WTs, dense_ent, vvec, vu_part, flag);

  softmax_z<true ><<<dim3(256), dim3(256), 0, stream>>>(wh, vu_part, d_out, flag);
  softmax_z<false><<<dim3(256), dim3(256), 0, stream>>>(wh, vu_part, d_out, flag);
}